// Round 9
// baseline (140.338 us; speedup 1.0000x reference)
//
#include <hip/hip_runtime.h>

// Attention_55336358642806: x@W_qkv+b -> 4-head causal attention -> @W_out+b
// B=16 S=1024 E=256 H=4 D=64.  All-MFMA bf16 pipeline, fp32 accumulation.
//
// GEMM v4 (this round): barrier-free wave-synchronous. B-panel 64x256 resident
// in LDS (ONE barrier total); per-wave PRIVATE A rings (3-deep, BK=32) staged
// via global_load_lds with counted per-wave vmcnt (no inter-wave sync in loop).
// INSTRUMENTATION: g1 grid-duplicated REP=8 (identical writes, benign) so its
// dispatch exceeds the ~42us fill kernels and shows full rocprof counters.
//
// ws layout (bytes):
//   [0,        393216)   W_qkvT bf16 [768][256]
//   [393216,   524288)   W_outT bf16 [256][256]
//   [524288, 17301504)   qk     bf16 [16384][512]  (Q cols 0..255, K 256..511;
//                                                   attn out overwrites Q cols)
//   [17301504,25690112)  Vt     bf16 [64 bh][16 kvt][64 d][64 kv]
//   [25690112,34078720)  xb     bf16 [16384][256]

typedef unsigned short ushort_t;
typedef __bf16 bf16x8 __attribute__((ext_vector_type(8)));
typedef __bf16 bf16x4 __attribute__((ext_vector_type(4)));
typedef unsigned short u16x8 __attribute__((ext_vector_type(8)));
typedef unsigned short u16x4 __attribute__((ext_vector_type(4)));
typedef float f32x4 __attribute__((ext_vector_type(4)));
typedef short s16x4 __attribute__((ext_vector_type(4)));

__device__ __forceinline__ ushort_t f2bf(float f) {
  unsigned u = __builtin_bit_cast(unsigned, f);
  u += 0x7fffu + ((u >> 16) & 1u);
  return (ushort_t)(u >> 16);
}

__device__ __forceinline__ void gload_lds16(const ushort_t* g, ushort_t* l) {
  __builtin_amdgcn_global_load_lds(
      (const __attribute__((address_space(1))) unsigned int*)g,
      (__attribute__((address_space(3))) unsigned int*)l, 16, 0, 0);
}

#define BARRIER_RAW() do { __builtin_amdgcn_s_barrier(); \
                           __builtin_amdgcn_sched_barrier(0); } while (0)

// 16x16x16 bf16 MFMA (A,B = 4 bf16 = 2 VGPR; C/D = 4 f32)
__device__ __forceinline__ f32x4 mfma16(bf16x4 a, bf16x4 b, f32x4 c) {
#if __has_builtin(__builtin_amdgcn_mfma_f32_16x16x16bf16_1k)
  return __builtin_amdgcn_mfma_f32_16x16x16bf16_1k(
      __builtin_bit_cast(s16x4, a), __builtin_bit_cast(s16x4, b), c, 0, 0, 0);
#elif __has_builtin(__builtin_amdgcn_mfma_f32_16x16x16_bf16)
  return __builtin_amdgcn_mfma_f32_16x16x16_bf16(a, b, c, 0, 0, 0);
#else
  f32x4 d = c;
  asm volatile("v_mfma_f32_16x16x16_bf16 %0, %1, %2, %0"
               : "+v"(d) : "v"(a), "v"(b));
  return d;
#endif
}

// ------------- kernel 0: convert x->bf16 + transpose weights ----------------
__global__ __launch_bounds__(256)
void convert_all(const float* __restrict__ x,
                 const float* __restrict__ Wq, const float* __restrict__ Wo,
                 ushort_t* __restrict__ xb,
                 ushort_t* __restrict__ WqT, ushort_t* __restrict__ WoT)
{
  int blk = blockIdx.x;
  if (blk < 2048) {                 // x: 8 floats/thread, coalesced
    const size_t base = (size_t)blk * 2048 + threadIdx.x * 8;
    float4 v0 = *(const float4*)&x[base];
    float4 v1 = *(const float4*)&x[base + 4];
    u16x8 ov;
    ov[0]=f2bf(v0.x); ov[1]=f2bf(v0.y); ov[2]=f2bf(v0.z); ov[3]=f2bf(v0.w);
    ov[4]=f2bf(v1.x); ov[5]=f2bf(v1.y); ov[6]=f2bf(v1.z); ov[7]=f2bf(v1.w);
    *(u16x8*)&xb[base] = ov;
    return;
  }
  blk -= 2048;                      // weights: LDS-tile transpose, coalesced
  __shared__ float t[64][65];
  const float* src; ushort_t* dst; int ld_src, k0, n0;
  if (blk < 48) { src = Wq; dst = WqT; ld_src = 768;
                  k0 = (blk / 12) * 64; n0 = (blk % 12) * 64; }
  else { blk -= 48; src = Wo; dst = WoT; ld_src = 256;
         k0 = (blk / 4) * 64; n0 = (blk % 4) * 64; }
  const int tr = threadIdx.x >> 6, tc = threadIdx.x & 63;
  #pragma unroll
  for (int i = 0; i < 16; ++i) {
    const int r = i * 4 + tr;
    t[r][tc] = src[(size_t)(k0 + r) * ld_src + n0 + tc];
  }
  __syncthreads();
  #pragma unroll
  for (int i = 0; i < 16; ++i) {
    const int r = i * 4 + tr;
    dst[(size_t)(n0 + r) * 256 + k0 + tc] = f2bf(t[tc][r]);
  }
}

// ---------------- GEMM v4: C[M][N] = A[M][256] * Bt[N][256]^T + bias --------
// Block: 4 waves, tile 256M x 64N; wave w owns rows [mBase+w*64, +64), all N.
// LDS: Bl[64][256] resident (32KB, ONE barrier); Al[4][3][64][32] per-wave
// rings (48KB). In-loop: NO barriers — per-wave counted vmcnt only.
// 8 steps of BK=32: stage(t+2) | vmcnt | 4 A-ds_read + 4 B-ds_read | 16 MFMA.
// OUT_MODE: 0 = qkv split (col<512 -> qk; col>=512 -> Vt via swapped MFMA,
// coalesced), 1 = f32 row-major.  NB = n-tiles.  REP = grid duplication
// (duplicate blocks write identical bytes; instrumentation only).
template<int OUT_MODE, int NB, int REP>
__global__ __launch_bounds__(256, 2)
void gemm_bias(const ushort_t* __restrict__ A, int ldA,
               const ushort_t* __restrict__ Bt,
               const float* __restrict__ bias,
               void* __restrict__ Outp, int ldOut,
               ushort_t* __restrict__ Vt)
{
  __shared__ ushort_t Bl[64][256];          // 32 KB; 16B-chunk c at c^(r&7)
  __shared__ ushort_t Al[4][3][64][32];     // 48 KB; chunk c at c^((r>>1)&3)

  const int tid = threadIdx.x;
  const int lane = tid & 63;
  const int w  = tid >> 6;
  const int l15 = lane & 15, g = lane >> 4;

  const int nwg = NB * 64;
  const int inner = (int)blockIdx.x % nwg;
  const int chunkXCD = nwg >> 3;
  const int gidx = (inner & 7) * chunkXCD + (inner >> 3);
  const int n0 = (gidx % NB) * 64;
  const int mBase = (gidx / NB) * 256;
  const int mw = mBase + w * 64;            // this wave's 64 rows
  const bool vmode = (OUT_MODE == 0) && (n0 >= 512);

  // ---- B resident stage (block-cooperative): 2048 chunks ----
  #pragma unroll
  for (int i = 0; i < 8; ++i) {
    const int L = i * 256 + tid;
    const int r = L >> 5, c = L & 31;
    gload_lds16(&Bt[(size_t)(n0 + r) * 256 + (c ^ (r & 7)) * 8],
                &Bl[0][0] + (size_t)L * 8);
  }
  // ---- A ring prologue (wave-private): slices 0,1 ----
  #pragma unroll
  for (int s = 0; s < 2; ++s)
    #pragma unroll
    for (int i = 0; i < 4; ++i) {
      const int L = i * 64 + lane;          // 256 chunks per slice
      const int r = L >> 2, c = L & 3;
      gload_lds16(&A[(size_t)(mw + r) * ldA + s*32 + (c ^ ((r >> 1) & 3)) * 8],
                  &Al[w][s][0][0] + (size_t)L * 8);
    }
  asm volatile("s_waitcnt vmcnt(8)" ::: "memory");  // own B chunks landed
  BARRIER_RAW();                                     // B visible to all waves

  f32x4 acc[4][4] = {};

  #pragma unroll
  for (int t = 0; t < 8; ++t) {             // K = 8 x 32, NO barriers
    if (t < 6) {                            // stage slice t+2 into ring
      #pragma unroll
      for (int i = 0; i < 4; ++i) {
        const int L = i * 64 + lane;
        const int r = L >> 2, c = L & 3;
        gload_lds16(&A[(size_t)(mw + r) * ldA + (t+2)*32
                       + (c ^ ((r >> 1) & 3)) * 8],
                    &Al[w][(t + 2) % 3][0][0] + (size_t)L * 8);
      }
    }
    // wait: slice t landed (per-wave FIFO vmcnt)
    if (t < 6)      asm volatile("s_waitcnt vmcnt(8)" ::: "memory");
    else if (t == 6) asm volatile("s_waitcnt vmcnt(4)" ::: "memory");
    else             asm volatile("s_waitcnt vmcnt(0)" ::: "memory");

    bf16x8 af[4], bfr[4];
    #pragma unroll
    for (int mi = 0; mi < 4; ++mi) {
      const int r = mi * 16 + l15;
      af[mi] = __builtin_bit_cast(bf16x8,
          *(const u16x8*)&Al[w][t % 3][r][(g ^ ((r >> 1) & 3)) * 8]);
    }
    #pragma unroll
    for (int ni = 0; ni < 4; ++ni) {
      const int r = ni * 16 + l15;
      bfr[ni] = __builtin_bit_cast(bf16x8,
          *(const u16x8*)&Bl[r][((t*4 + g) ^ (r & 7)) * 8]);
    }
    if (vmode) {
      #pragma unroll
      for (int mi = 0; mi < 4; ++mi)
        #pragma unroll
        for (int ni = 0; ni < 4; ++ni)
          acc[mi][ni] = __builtin_amdgcn_mfma_f32_16x16x32_bf16(
                            bfr[ni], af[mi], acc[mi][ni], 0, 0, 0);
    } else {
      #pragma unroll
      for (int mi = 0; mi < 4; ++mi)
        #pragma unroll
        for (int ni = 0; ni < 4; ++ni)
          acc[mi][ni] = __builtin_amdgcn_mfma_f32_16x16x32_bf16(
                            af[mi], bfr[ni], acc[mi][ni], 0, 0, 0);
    }
  }

  // ---- epilogue: C/D layout row = g*4+r, col = l15 ----
  #pragma unroll
  for (int mi = 0; mi < 4; ++mi)
    #pragma unroll
    for (int ni = 0; ni < 4; ++ni) {
      if (!vmode) {
        const int col = n0 + ni * 16 + l15;
        const float bv = bias[col];
        #pragma unroll
        for (int r = 0; r < 4; ++r) {
          const int row = mw + mi * 16 + g * 4 + r;
          const float v = acc[mi][ni][r] + bv;
          if (OUT_MODE == 1)
            ((float*)Outp)[(size_t)row * ldOut + col] = v;
          else
            ((ushort_t*)Outp)[(size_t)row * 512 + col] = f2bf(v);
        }
      } else {
        // swapped MFMA: D row = n (d-dim), D col = m (seq) -> coalesced Vt
        const int hh = (n0 - 512) >> 6;
        const int m = mw + mi * 16 + l15;
        const int bb = m >> 10, ss = m & 1023;
        ushort_t* vbase =
            &Vt[(size_t)(((bb*4 + hh)*16 + (ss >> 6)) * 4096) + (ss & 63)];
        #pragma unroll
        for (int r = 0; r < 4; ++r) {
          const int nn = n0 + ni * 16 + g * 4 + r;     // 512..767
          const float v = acc[mi][ni][r] + bias[nn];
          vbase[(size_t)((nn - 512) & 63) * 64] = f2bf(v);
        }
      }
    }
}

// ---------------- kernel 2: causal flash attention (r8, unchanged) ----------
__global__ __launch_bounds__(256, 2)
void attn_kernel(ushort_t* __restrict__ qk, const ushort_t* __restrict__ Vt)
{
  __shared__ ushort_t K_lds[3][64][64];   // 24 KB ring
  __shared__ ushort_t V_lds[3][64][64];   // 24 KB ring (V^T tiles)

  const int lid = blockIdx.x;
  const int p   = (lid >> 3) & 7;
  const int bh  = (lid & 7) + ((lid >> 6) << 3);
  const int h = bh & 3, b = bh >> 2;
  const int qtA = p, qtB = 15 - p;

  const int tid = threadIdx.x;
  const int lane = tid & 63;
  const int w = tid >> 6;
  const int l15 = lane & 15, g = lane >> 4;

  const size_t rowbase = (size_t)b * 1024;
  const int qc = h * 64, kc = 256 + h * 64;
  const ushort_t* Vtt = Vt + (size_t)bh * 16 * 4096;

  bf16x8 qfA[2], qfB[2];
  {
    const size_t ra = rowbase + qtA*64 + w*16 + l15;
    const size_t rb = rowbase + qtB*64 + w*16 + l15;
    #pragma unroll
    for (int ks = 0; ks < 2; ++ks) {
      qfA[ks] = __builtin_bit_cast(bf16x8,
                  *(const u16x8*)&qk[ra*512 + qc + ks*32 + g*8]);
      qfB[ks] = __builtin_bit_cast(bf16x8,
                  *(const u16x8*)&qk[rb*512 + qc + ks*32 + g*8]);
    }
  }

  f32x4 oA[4] = {}, oB[4] = {};
  float lsA = 0.f, lsB = 0.f;
  const int qgA = qtA*64 + w*16 + l15;
  const int qgB = qtB*64 + w*16 + l15;

  auto stage = [&](int bi, int kt) {
    const int kv0 = kt * 64;
    const ushort_t* vtile = Vtt + kt * 4096;
    #pragma unroll
    for (int ri = 0; ri < 2; ++ri) {
      const int L = ri*256 + tid;
      const int r = L >> 3;
      gload_lds16(&qk[(rowbase + kv0 + r)*512 + kc + ((L & 7) ^ (r & 7))*8],
                  &K_lds[bi][0][0] + (size_t)L*8);
      gload_lds16(&vtile[r*64 + ((L & 7) ^ ((r >> 1) & 7))*8],
                  &V_lds[bi][0][0] + (size_t)L*8);
    }
  };

  stage(0, 0);
  stage(1, 1);
  asm volatile("s_waitcnt vmcnt(4)" ::: "memory");
  BARRIER_RAW();

  for (int kt = 0; kt <= qtB; ++kt) {
    const int cur = kt % 3;
    stage((kt + 2) % 3, (kt + 2 <= qtB) ? kt + 2 : qtB);

    bf16x8 kf[2][4];
    #pragma unroll
    for (int ks = 0; ks < 2; ++ks)
      #pragma unroll
      for (int ni = 0; ni < 4; ++ni) {
        const int row = ni*16 + l15;
        kf[ks][ni] = __builtin_bit_cast(bf16x8,
            *(const u16x8*)&K_lds[cur][row][(((ks*4 + g) ^ (row & 7))) * 8]);
      }
    bf16x4 vf[4][4];
    #pragma unroll
    for (int ni = 0; ni < 4; ++ni)
      #pragma unroll
      for (int da = 0; da < 4; ++da) {
        const int row = da*16 + l15;
        const int phys = (ni*2 + (g >> 1)) ^ ((row >> 1) & 7);
        vf[ni][da] = __builtin_bit_cast(bf16x4,
            *(const u16x4*)&V_lds[cur][row][phys*8 + (g & 1)*4]);
      }

    const int kv0 = kt * 64;
    const int g4 = g * 4;

    auto tile_step = [&](const bf16x8 (&qf)[2], f32x4 (&o)[4], float &ls,
                         int qg, bool diag) {
      f32x4 s[4] = {};
      #pragma unroll
      for (int ks = 0; ks < 2; ++ks)
        #pragma unroll
        for (int ni = 0; ni < 4; ++ni)
          s[ni] = __builtin_amdgcn_mfma_f32_16x16x32_bf16(kf[ks][ni], qf[ks],
                                                          s[ni], 0, 0, 0);
      bf16x4 pn[4];
      #pragma unroll
      for (int ni = 0; ni < 4; ++ni)
        #pragma unroll
        for (int r = 0; r < 4; ++r) {
          float e = __expf(fmaf(s[ni][r], 0.125f, -10.0f));
          if (diag) e = (kv0 + ni*16 + g4 + r <= qg) ? e : 0.0f;
          ls += e;
          pn[ni][r] = (__bf16)e;
        }
      #pragma unroll
      for (int ni = 0; ni < 4; ++ni)
        #pragma unroll
        for (int da = 0; da < 4; ++da)
          o[da] = mfma16(vf[ni][da], pn[ni], o[da]);
    };

    tile_step(qfB, oB, lsB, qgB, kt == qtB);
    if (kt <= qtA) tile_step(qfA, oA, lsA, qgA, kt == qtA);

    asm volatile("s_waitcnt vmcnt(4)" ::: "memory");
    BARRIER_RAW();
  }

  asm volatile("s_nop 7\n\ts_nop 7" :::);

  lsA += __shfl_xor(lsA, 16); lsA += __shfl_xor(lsA, 32);
  lsB += __shfl_xor(lsB, 16); lsB += __shfl_xor(lsB, 32);
  const float invA = 1.f / lsA;
  const float invB = 1.f / lsB;

  {
    const size_t rowA = rowbase + (size_t)qgA;
    const size_t rowB = rowbase + (size_t)qgB;
    #pragma unroll
    for (int da = 0; da < 4; ++da) {
      u16x4 ovA, ovB;
      #pragma unroll
      for (int r = 0; r < 4; ++r) {
        ovA[r] = f2bf(oA[da][r] * invA);
        ovB[r] = f2bf(oB[da][r] * invB);
      }
      *(u16x4*)&qk[rowA*512 + qc + da*16 + g*4] = ovA;
      *(u16x4*)&qk[rowB*512 + qc + da*16 + g*4] = ovB;
    }
  }
}

// ---------------- launcher --------------------------------------------------
extern "C" void kernel_launch(void* const* d_in, const int* in_sizes, int n_in,
                              void* d_out, int out_size, void* d_ws, size_t ws_size,
                              hipStream_t stream)
{
  const float* x     = (const float*)d_in[0];
  const float* W_qkv = (const float*)d_in[1];
  const float* b_qkv = (const float*)d_in[2];
  const float* W_out = (const float*)d_in[3];
  const float* b_out = (const float*)d_in[4];
  float* out = (float*)d_out;

  char* ws = (char*)d_ws;
  ushort_t* WqT = (ushort_t*)ws;                         // [768][256]
  ushort_t* WoT = (ushort_t*)(ws + 393216);              // [256][256]
  ushort_t* qk  = (ushort_t*)(ws + 524288);              // [16384][512]
  ushort_t* Vt  = (ushort_t*)(ws + 17301504);            // [64][16][64][64]
  ushort_t* xb  = (ushort_t*)(ws + 25690112);            // [16384][256]

  convert_all<<<dim3(2112), dim3(256), 0, stream>>>(x, W_qkv, W_out, xb, WqT, WoT);
  // QKV projection, REP=8 instrumentation (duplicate blocks, identical writes)
  gemm_bias<0, 12, 8><<<dim3(8 * 768), dim3(256), 0, stream>>>(
      xb, 256, WqT, b_qkv, qk, 512, Vt);
  // causal flash attention (unchanged)
  attn_kernel<<<dim3(512), dim3(256), 0, stream>>>(qk, Vt);
  // output projection
  gemm_bias<1, 4, 1><<<dim3(256), dim3(256), 0, stream>>>(
      qk, 512, WoT, b_out, out, 256, nullptr);
}

// Round 10
// 95.268 us; speedup vs baseline: 1.4731x; 1.4731x over previous
//
#include <hip/hip_runtime.h>

// Attention_55336358642806: x@W_qkv+b -> 4-head causal attention -> @W_out+b
// B=16 S=1024 E=256 H=4 D=64.  All-MFMA bf16 pipeline, fp32 accumulation.
//
// GEMM v4: barrier-free wave-synchronous (proven r9: unit ~14us, 3x the
// barrier version). B-panel 64x256 resident in LDS (ONE barrier total);
// per-wave PRIVATE A rings (3-deep, BK=32) via global_load_lds + counted
// per-wave vmcnt.
// INSTRUMENTATION this round: attn REP=4 (dup blocks compute, skip stores)
// so its dispatch exceeds the ~42us fill kernels and shows full counters.
//
// ws layout (bytes):
//   [0,        393216)   W_qkvT bf16 [768][256]
//   [393216,   524288)   W_outT bf16 [256][256]
//   [524288, 17301504)   qk     bf16 [16384][512]  (Q cols 0..255, K 256..511;
//                                                   attn out overwrites Q cols)
//   [17301504,25690112)  Vt     bf16 [64 bh][16 kvt][64 d][64 kv]
//   [25690112,34078720)  xb     bf16 [16384][256]

typedef unsigned short ushort_t;
typedef __bf16 bf16x8 __attribute__((ext_vector_type(8)));
typedef __bf16 bf16x4 __attribute__((ext_vector_type(4)));
typedef unsigned short u16x8 __attribute__((ext_vector_type(8)));
typedef unsigned short u16x4 __attribute__((ext_vector_type(4)));
typedef float f32x4 __attribute__((ext_vector_type(4)));
typedef short s16x4 __attribute__((ext_vector_type(4)));

// HW bf16 convert (RNE on gfx950, single v_cvt instruction)
__device__ __forceinline__ ushort_t f2bf(float f) {
  __bf16 h = (__bf16)f;
  return __builtin_bit_cast(ushort_t, h);
}

__device__ __forceinline__ void gload_lds16(const ushort_t* g, ushort_t* l) {
  __builtin_amdgcn_global_load_lds(
      (const __attribute__((address_space(1))) unsigned int*)g,
      (__attribute__((address_space(3))) unsigned int*)l, 16, 0, 0);
}

#define BARRIER_RAW() do { __builtin_amdgcn_s_barrier(); \
                           __builtin_amdgcn_sched_barrier(0); } while (0)

// 16x16x16 bf16 MFMA (A,B = 4 bf16 = 2 VGPR; C/D = 4 f32)
__device__ __forceinline__ f32x4 mfma16(bf16x4 a, bf16x4 b, f32x4 c) {
#if __has_builtin(__builtin_amdgcn_mfma_f32_16x16x16bf16_1k)
  return __builtin_amdgcn_mfma_f32_16x16x16bf16_1k(
      __builtin_bit_cast(s16x4, a), __builtin_bit_cast(s16x4, b), c, 0, 0, 0);
#elif __has_builtin(__builtin_amdgcn_mfma_f32_16x16x16_bf16)
  return __builtin_amdgcn_mfma_f32_16x16x16_bf16(a, b, c, 0, 0, 0);
#else
  f32x4 d = c;
  asm volatile("v_mfma_f32_16x16x16_bf16 %0, %1, %2, %0"
               : "+v"(d) : "v"(a), "v"(b));
  return d;
#endif
}

// ------------- kernel 0: convert x->bf16 + transpose weights ----------------
__global__ __launch_bounds__(256)
void convert_all(const float* __restrict__ x,
                 const float* __restrict__ Wq, const float* __restrict__ Wo,
                 ushort_t* __restrict__ xb,
                 ushort_t* __restrict__ WqT, ushort_t* __restrict__ WoT)
{
  int blk = blockIdx.x;
  if (blk < 2048) {                 // x: 8 floats/thread, coalesced
    const size_t base = (size_t)blk * 2048 + threadIdx.x * 8;
    float4 v0 = *(const float4*)&x[base];
    float4 v1 = *(const float4*)&x[base + 4];
    u16x8 ov;
    ov[0]=f2bf(v0.x); ov[1]=f2bf(v0.y); ov[2]=f2bf(v0.z); ov[3]=f2bf(v0.w);
    ov[4]=f2bf(v1.x); ov[5]=f2bf(v1.y); ov[6]=f2bf(v1.z); ov[7]=f2bf(v1.w);
    *(u16x8*)&xb[base] = ov;
    return;
  }
  blk -= 2048;                      // weights: LDS-tile transpose, coalesced
  __shared__ float t[64][65];
  const float* src; ushort_t* dst; int ld_src, k0, n0;
  if (blk < 48) { src = Wq; dst = WqT; ld_src = 768;
                  k0 = (blk / 12) * 64; n0 = (blk % 12) * 64; }
  else { blk -= 48; src = Wo; dst = WoT; ld_src = 256;
         k0 = (blk / 4) * 64; n0 = (blk % 4) * 64; }
  const int tr = threadIdx.x >> 6, tc = threadIdx.x & 63;
  #pragma unroll
  for (int i = 0; i < 16; ++i) {
    const int r = i * 4 + tr;
    t[r][tc] = src[(size_t)(k0 + r) * ld_src + n0 + tc];
  }
  __syncthreads();
  #pragma unroll
  for (int i = 0; i < 16; ++i) {
    const int r = i * 4 + tr;
    dst[(size_t)(n0 + r) * 256 + k0 + tc] = f2bf(t[tc][r]);
  }
}

// ---------------- GEMM v4 (r9 structure, REP=1) -----------------------------
template<int OUT_MODE, int NB, int REP>
__global__ __launch_bounds__(256, 2)
void gemm_bias(const ushort_t* __restrict__ A, int ldA,
               const ushort_t* __restrict__ Bt,
               const float* __restrict__ bias,
               void* __restrict__ Outp, int ldOut,
               ushort_t* __restrict__ Vt)
{
  __shared__ ushort_t Bl[64][256];          // 32 KB; 16B-chunk c at c^(r&7)
  __shared__ ushort_t Al[4][3][64][32];     // 48 KB; chunk c at c^((r>>1)&3)

  const int tid = threadIdx.x;
  const int lane = tid & 63;
  const int w  = tid >> 6;
  const int l15 = lane & 15, g = lane >> 4;

  const int nwg = NB * 64;
  const int inner = (int)blockIdx.x % nwg;
  const int chunkXCD = nwg >> 3;
  const int gidx = (inner & 7) * chunkXCD + (inner >> 3);
  const int n0 = (gidx % NB) * 64;
  const int mBase = (gidx / NB) * 256;
  const int mw = mBase + w * 64;            // this wave's 64 rows
  const bool vmode = (OUT_MODE == 0) && (n0 >= 512);

  // ---- B resident stage (block-cooperative): 2048 chunks ----
  #pragma unroll
  for (int i = 0; i < 8; ++i) {
    const int L = i * 256 + tid;
    const int r = L >> 5, c = L & 31;
    gload_lds16(&Bt[(size_t)(n0 + r) * 256 + (c ^ (r & 7)) * 8],
                &Bl[0][0] + (size_t)L * 8);
  }
  // ---- A ring prologue (wave-private): slices 0,1 ----
  #pragma unroll
  for (int s = 0; s < 2; ++s)
    #pragma unroll
    for (int i = 0; i < 4; ++i) {
      const int L = i * 64 + lane;          // 256 chunks per slice
      const int r = L >> 2, c = L & 3;
      gload_lds16(&A[(size_t)(mw + r) * ldA + s*32 + (c ^ ((r >> 1) & 3)) * 8],
                  &Al[w][s][0][0] + (size_t)L * 8);
    }
  asm volatile("s_waitcnt vmcnt(8)" ::: "memory");  // own B chunks landed
  BARRIER_RAW();                                     // B visible to all waves

  f32x4 acc[4][4] = {};

  #pragma unroll
  for (int t = 0; t < 8; ++t) {             // K = 8 x 32, NO barriers
    if (t < 6) {                            // stage slice t+2 into ring
      #pragma unroll
      for (int i = 0; i < 4; ++i) {
        const int L = i * 64 + lane;
        const int r = L >> 2, c = L & 3;
        gload_lds16(&A[(size_t)(mw + r) * ldA + (t+2)*32
                       + (c ^ ((r >> 1) & 3)) * 8],
                    &Al[w][(t + 2) % 3][0][0] + (size_t)L * 8);
      }
    }
    if (t < 6)      asm volatile("s_waitcnt vmcnt(8)" ::: "memory");
    else if (t == 6) asm volatile("s_waitcnt vmcnt(4)" ::: "memory");
    else             asm volatile("s_waitcnt vmcnt(0)" ::: "memory");

    bf16x8 af[4], bfr[4];
    #pragma unroll
    for (int mi = 0; mi < 4; ++mi) {
      const int r = mi * 16 + l15;
      af[mi] = __builtin_bit_cast(bf16x8,
          *(const u16x8*)&Al[w][t % 3][r][(g ^ ((r >> 1) & 3)) * 8]);
    }
    #pragma unroll
    for (int ni = 0; ni < 4; ++ni) {
      const int r = ni * 16 + l15;
      bfr[ni] = __builtin_bit_cast(bf16x8,
          *(const u16x8*)&Bl[r][((t*4 + g) ^ (r & 7)) * 8]);
    }
    if (vmode) {
      #pragma unroll
      for (int mi = 0; mi < 4; ++mi)
        #pragma unroll
        for (int ni = 0; ni < 4; ++ni)
          acc[mi][ni] = __builtin_amdgcn_mfma_f32_16x16x32_bf16(
                            bfr[ni], af[mi], acc[mi][ni], 0, 0, 0);
    } else {
      #pragma unroll
      for (int mi = 0; mi < 4; ++mi)
        #pragma unroll
        for (int ni = 0; ni < 4; ++ni)
          acc[mi][ni] = __builtin_amdgcn_mfma_f32_16x16x32_bf16(
                            af[mi], bfr[ni], acc[mi][ni], 0, 0, 0);
    }
  }

  // ---- epilogue: C/D layout row = g*4+r, col = l15 ----
  #pragma unroll
  for (int mi = 0; mi < 4; ++mi)
    #pragma unroll
    for (int ni = 0; ni < 4; ++ni) {
      if (!vmode) {
        const int col = n0 + ni * 16 + l15;
        const float bv = bias[col];
        #pragma unroll
        for (int r = 0; r < 4; ++r) {
          const int row = mw + mi * 16 + g * 4 + r;
          const float v = acc[mi][ni][r] + bv;
          if (OUT_MODE == 1)
            ((float*)Outp)[(size_t)row * ldOut + col] = v;
          else
            ((ushort_t*)Outp)[(size_t)row * 512 + col] = f2bf(v);
        }
      } else {
        // swapped MFMA: D row = n (d-dim), D col = m (seq) -> coalesced Vt
        const int hh = (n0 - 512) >> 6;
        const int m = mw + mi * 16 + l15;
        const int bb = m >> 10, ss = m & 1023;
        ushort_t* vbase =
            &Vt[(size_t)(((bb*4 + hh)*16 + (ss >> 6)) * 4096) + (ss & 63)];
        #pragma unroll
        for (int r = 0; r < 4; ++r) {
          const int nn = n0 + ni * 16 + g * 4 + r;     // 512..767
          const float v = acc[mi][ni][r] + bias[nn];
          vbase[(size_t)((nn - 512) & 63) * 64] = f2bf(v);
        }
      }
    }
}

// ---------------- kernel 2: causal flash attention (swapped-operand) --------
// REP instrumentation: grid = REP*512; rep = lid>>9 blocks do the identical
// compute but SKIP final stores (runtime guard -> no DCE, no write race;
// dup reads of Q racing rep0's O-writes are benign since dups store nothing).
template<int REP>
__global__ __launch_bounds__(256, 2)
void attn_kernel(ushort_t* __restrict__ qk, const ushort_t* __restrict__ Vt)
{
  __shared__ ushort_t K_lds[3][64][64];   // 24 KB ring
  __shared__ ushort_t V_lds[3][64][64];   // 24 KB ring (V^T tiles)

  const int rep = (int)blockIdx.x >> 9;
  const int lid = (int)blockIdx.x & 511;
  const int p   = (lid >> 3) & 7;
  const int bh  = (lid & 7) + ((lid >> 6) << 3);
  const int h = bh & 3, b = bh >> 2;
  const int qtA = p, qtB = 15 - p;

  const int tid = threadIdx.x;
  const int lane = tid & 63;
  const int w = tid >> 6;
  const int l15 = lane & 15, g = lane >> 4;

  const size_t rowbase = (size_t)b * 1024;
  const int qc = h * 64, kc = 256 + h * 64;
  const ushort_t* Vtt = Vt + (size_t)bh * 16 * 4096;

  bf16x8 qfA[2], qfB[2];
  {
    const size_t ra = rowbase + qtA*64 + w*16 + l15;
    const size_t rb = rowbase + qtB*64 + w*16 + l15;
    #pragma unroll
    for (int ks = 0; ks < 2; ++ks) {
      qfA[ks] = __builtin_bit_cast(bf16x8,
                  *(const u16x8*)&qk[ra*512 + qc + ks*32 + g*8]);
      qfB[ks] = __builtin_bit_cast(bf16x8,
                  *(const u16x8*)&qk[rb*512 + qc + ks*32 + g*8]);
    }
  }

  f32x4 oA[4] = {}, oB[4] = {};
  float lsA = 0.f, lsB = 0.f;
  const int qgA = qtA*64 + w*16 + l15;
  const int qgB = qtB*64 + w*16 + l15;

  auto stage = [&](int bi, int kt) {
    const int kv0 = kt * 64;
    const ushort_t* vtile = Vtt + kt * 4096;
    #pragma unroll
    for (int ri = 0; ri < 2; ++ri) {
      const int L = ri*256 + tid;
      const int r = L >> 3;
      gload_lds16(&qk[(rowbase + kv0 + r)*512 + kc + ((L & 7) ^ (r & 7))*8],
                  &K_lds[bi][0][0] + (size_t)L*8);
      gload_lds16(&vtile[r*64 + ((L & 7) ^ ((r >> 1) & 7))*8],
                  &V_lds[bi][0][0] + (size_t)L*8);
    }
  };

  stage(0, 0);
  stage(1, 1);
  asm volatile("s_waitcnt vmcnt(4)" ::: "memory");
  BARRIER_RAW();

  for (int kt = 0; kt <= qtB; ++kt) {
    const int cur = kt % 3;
    stage((kt + 2) % 3, (kt + 2 <= qtB) ? kt + 2 : qtB);

    bf16x8 kf[2][4];
    #pragma unroll
    for (int ks = 0; ks < 2; ++ks)
      #pragma unroll
      for (int ni = 0; ni < 4; ++ni) {
        const int row = ni*16 + l15;
        kf[ks][ni] = __builtin_bit_cast(bf16x8,
            *(const u16x8*)&K_lds[cur][row][(((ks*4 + g) ^ (row & 7))) * 8]);
      }
    bf16x4 vf[4][4];
    #pragma unroll
    for (int ni = 0; ni < 4; ++ni)
      #pragma unroll
      for (int da = 0; da < 4; ++da) {
        const int row = da*16 + l15;
        const int phys = (ni*2 + (g >> 1)) ^ ((row >> 1) & 7);
        vf[ni][da] = __builtin_bit_cast(bf16x4,
            *(const u16x4*)&V_lds[cur][row][phys*8 + (g & 1)*4]);
      }

    const int kv0 = kt * 64;
    const int g4 = g * 4;

    auto tile_step = [&](const bf16x8 (&qf)[2], f32x4 (&o)[4], float &ls,
                         int qg, bool diag) {
      f32x4 s[4] = {};
      #pragma unroll
      for (int ks = 0; ks < 2; ++ks)
        #pragma unroll
        for (int ni = 0; ni < 4; ++ni)
          s[ni] = __builtin_amdgcn_mfma_f32_16x16x32_bf16(kf[ks][ni], qf[ks],
                                                          s[ni], 0, 0, 0);
      bf16x4 pn[4];
      #pragma unroll
      for (int ni = 0; ni < 4; ++ni)
        #pragma unroll
        for (int r = 0; r < 4; ++r) {
          float e = __expf(fmaf(s[ni][r], 0.125f, -10.0f));
          if (diag) e = (kv0 + ni*16 + g4 + r <= qg) ? e : 0.0f;
          ls += e;
          pn[ni][r] = (__bf16)e;
        }
      #pragma unroll
      for (int ni = 0; ni < 4; ++ni)
        #pragma unroll
        for (int da = 0; da < 4; ++da)
          o[da] = mfma16(vf[ni][da], pn[ni], o[da]);
    };

    tile_step(qfB, oB, lsB, qgB, kt == qtB);
    if (kt <= qtA) tile_step(qfA, oA, lsA, qgA, kt == qtA);

    asm volatile("s_waitcnt vmcnt(4)" ::: "memory");
    BARRIER_RAW();
  }

  asm volatile("s_nop 7\n\ts_nop 7" :::);

  lsA += __shfl_xor(lsA, 16); lsA += __shfl_xor(lsA, 32);
  lsB += __shfl_xor(lsB, 16); lsB += __shfl_xor(lsB, 32);
  const float invA = 1.f / lsA;
  const float invB = 1.f / lsB;

  if (rep == 0) {                    // dups compute but never store
    const size_t rowA = rowbase + (size_t)qgA;
    const size_t rowB = rowbase + (size_t)qgB;
    #pragma unroll
    for (int da = 0; da < 4; ++da) {
      u16x4 ovA, ovB;
      #pragma unroll
      for (int r = 0; r < 4; ++r) {
        ovA[r] = f2bf(oA[da][r] * invA);
        ovB[r] = f2bf(oB[da][r] * invB);
      }
      *(u16x4*)&qk[rowA*512 + qc + da*16 + g*4] = ovA;
      *(u16x4*)&qk[rowB*512 + qc + da*16 + g*4] = ovB;
    }
  }
}

// ---------------- launcher --------------------------------------------------
extern "C" void kernel_launch(void* const* d_in, const int* in_sizes, int n_in,
                              void* d_out, int out_size, void* d_ws, size_t ws_size,
                              hipStream_t stream)
{
  const float* x     = (const float*)d_in[0];
  const float* W_qkv = (const float*)d_in[1];
  const float* b_qkv = (const float*)d_in[2];
  const float* W_out = (const float*)d_in[3];
  const float* b_out = (const float*)d_in[4];
  float* out = (float*)d_out;

  char* ws = (char*)d_ws;
  ushort_t* WqT = (ushort_t*)ws;                         // [768][256]
  ushort_t* WoT = (ushort_t*)(ws + 393216);              // [256][256]
  ushort_t* qk  = (ushort_t*)(ws + 524288);              // [16384][512]
  ushort_t* Vt  = (ushort_t*)(ws + 17301504);            // [64][16][64][64]
  ushort_t* xb  = (ushort_t*)(ws + 25690112);            // [16384][256]

  convert_all<<<dim3(2112), dim3(256), 0, stream>>>(x, W_qkv, W_out, xb, WqT, WoT);
  // QKV projection (REP=1, banked)
  gemm_bias<0, 12, 1><<<dim3(768), dim3(256), 0, stream>>>(
      xb, 256, WqT, b_qkv, qk, 512, Vt);
  // causal flash attention, REP=4 instrumentation (dups skip stores)
  attn_kernel<4><<<dim3(4 * 512), dim3(256), 0, stream>>>(qk, Vt);
  // output projection
  gemm_bias<1, 4, 1><<<dim3(256), dim3(256), 0, stream>>>(
      qk, 512, WoT, b_out, out, 256, nullptr);
}

// Round 11
// 71.730 us; speedup vs baseline: 1.9565x; 1.3281x over previous
//
#include <hip/hip_runtime.h>

// Attention_55336358642806: x@W_qkv+b -> 4-head causal attention -> @W_out+b
// B=16 S=1024 E=256 H=4 D=64.  All-MFMA bf16 pipeline, fp32 accumulation.
//
// attn v3 (this round): unpaired q-tiles (1024 blocks, 3 blocks/CU), K via
// gload_lds XOR-swizzled ring (proven conflict-free), V REG-STAGED into
// padded [64][72] LDS (row stride 144B puts row bits into the bank index ->
// b64 V reads at floor; the old stride-64 layout was a 4-way conflict on all
// 16 reads/step = the 1.6M SQ_LDS_BANK_CONFLICT seen in r10).  Counted-vmcnt
// pipeline, raw barriers, exp2f softmax.
//
// ws layout (bytes):
//   [0,        393216)   W_qkvT bf16 [768][256]
//   [393216,   524288)   W_outT bf16 [256][256]
//   [524288, 17301504)   qk     bf16 [16384][512]  (Q cols 0..255, K 256..511;
//                                                   attn out overwrites Q cols)
//   [17301504,25690112)  Vt     bf16 [64 bh][16 kvt][64 d][64 kv]
//   [25690112,34078720)  xb     bf16 [16384][256]

typedef unsigned short ushort_t;
typedef __bf16 bf16x8 __attribute__((ext_vector_type(8)));
typedef __bf16 bf16x4 __attribute__((ext_vector_type(4)));
typedef unsigned short u16x8 __attribute__((ext_vector_type(8)));
typedef unsigned short u16x4 __attribute__((ext_vector_type(4)));
typedef float f32x4 __attribute__((ext_vector_type(4)));
typedef short s16x4 __attribute__((ext_vector_type(4)));

// HW bf16 convert (RNE on gfx950)
__device__ __forceinline__ ushort_t f2bf(float f) {
  __bf16 h = (__bf16)f;
  return __builtin_bit_cast(ushort_t, h);
}

__device__ __forceinline__ void gload_lds16(const ushort_t* g, ushort_t* l) {
  __builtin_amdgcn_global_load_lds(
      (const __attribute__((address_space(1))) unsigned int*)g,
      (__attribute__((address_space(3))) unsigned int*)l, 16, 0, 0);
}

#define BARRIER_RAW() do { __builtin_amdgcn_s_barrier(); \
                           __builtin_amdgcn_sched_barrier(0); } while (0)

// 16x16x16 bf16 MFMA
__device__ __forceinline__ f32x4 mfma16(bf16x4 a, bf16x4 b, f32x4 c) {
#if __has_builtin(__builtin_amdgcn_mfma_f32_16x16x16bf16_1k)
  return __builtin_amdgcn_mfma_f32_16x16x16bf16_1k(
      __builtin_bit_cast(s16x4, a), __builtin_bit_cast(s16x4, b), c, 0, 0, 0);
#elif __has_builtin(__builtin_amdgcn_mfma_f32_16x16x16_bf16)
  return __builtin_amdgcn_mfma_f32_16x16x16_bf16(a, b, c, 0, 0, 0);
#else
  f32x4 d = c;
  asm volatile("v_mfma_f32_16x16x16_bf16 %0, %1, %2, %0"
               : "+v"(d) : "v"(a), "v"(b));
  return d;
#endif
}

// ------------- kernel 0: convert x->bf16 + transpose weights ----------------
__global__ __launch_bounds__(256)
void convert_all(const float* __restrict__ x,
                 const float* __restrict__ Wq, const float* __restrict__ Wo,
                 ushort_t* __restrict__ xb,
                 ushort_t* __restrict__ WqT, ushort_t* __restrict__ WoT)
{
  int blk = blockIdx.x;
  if (blk < 2048) {                 // x: 8 floats/thread, coalesced
    const size_t base = (size_t)blk * 2048 + threadIdx.x * 8;
    float4 v0 = *(const float4*)&x[base];
    float4 v1 = *(const float4*)&x[base + 4];
    u16x8 ov;
    ov[0]=f2bf(v0.x); ov[1]=f2bf(v0.y); ov[2]=f2bf(v0.z); ov[3]=f2bf(v0.w);
    ov[4]=f2bf(v1.x); ov[5]=f2bf(v1.y); ov[6]=f2bf(v1.z); ov[7]=f2bf(v1.w);
    *(u16x8*)&xb[base] = ov;
    return;
  }
  blk -= 2048;                      // weights: LDS-tile transpose, coalesced
  __shared__ float t[64][65];
  const float* src; ushort_t* dst; int ld_src, k0, n0;
  if (blk < 48) { src = Wq; dst = WqT; ld_src = 768;
                  k0 = (blk / 12) * 64; n0 = (blk % 12) * 64; }
  else { blk -= 48; src = Wo; dst = WoT; ld_src = 256;
         k0 = (blk / 4) * 64; n0 = (blk % 4) * 64; }
  const int tr = threadIdx.x >> 6, tc = threadIdx.x & 63;
  #pragma unroll
  for (int i = 0; i < 16; ++i) {
    const int r = i * 4 + tr;
    t[r][tc] = src[(size_t)(k0 + r) * ld_src + n0 + tc];
  }
  __syncthreads();
  #pragma unroll
  for (int i = 0; i < 16; ++i) {
    const int r = i * 4 + tr;
    dst[(size_t)(n0 + r) * 256 + k0 + tc] = f2bf(t[tc][r]);
  }
}

// ---------------- GEMM v4 (r9/r10 structure, unchanged) ---------------------
template<int OUT_MODE, int NB>    // OUT_MODE: 0 = qkv split, 1 = f32 row-major
__global__ __launch_bounds__(256, 2)
void gemm_bias(const ushort_t* __restrict__ A, int ldA,
               const ushort_t* __restrict__ Bt,
               const float* __restrict__ bias,
               void* __restrict__ Outp, int ldOut,
               ushort_t* __restrict__ Vt)
{
  __shared__ ushort_t Bl[64][256];          // 32 KB; 16B-chunk c at c^(r&7)
  __shared__ ushort_t Al[4][3][64][32];     // 48 KB; chunk c at c^((r>>1)&3)

  const int tid = threadIdx.x;
  const int lane = tid & 63;
  const int w  = tid >> 6;
  const int l15 = lane & 15, g = lane >> 4;

  const int nwg = NB * 64;
  const int inner = (int)blockIdx.x % nwg;
  const int chunkXCD = nwg >> 3;
  const int gidx = (inner & 7) * chunkXCD + (inner >> 3);
  const int n0 = (gidx % NB) * 64;
  const int mBase = (gidx / NB) * 256;
  const int mw = mBase + w * 64;            // this wave's 64 rows
  const bool vmode = (OUT_MODE == 0) && (n0 >= 512);

  #pragma unroll
  for (int i = 0; i < 8; ++i) {
    const int L = i * 256 + tid;
    const int r = L >> 5, c = L & 31;
    gload_lds16(&Bt[(size_t)(n0 + r) * 256 + (c ^ (r & 7)) * 8],
                &Bl[0][0] + (size_t)L * 8);
  }
  #pragma unroll
  for (int s = 0; s < 2; ++s)
    #pragma unroll
    for (int i = 0; i < 4; ++i) {
      const int L = i * 64 + lane;          // 256 chunks per slice
      const int r = L >> 2, c = L & 3;
      gload_lds16(&A[(size_t)(mw + r) * ldA + s*32 + (c ^ ((r >> 1) & 3)) * 8],
                  &Al[w][s][0][0] + (size_t)L * 8);
    }
  asm volatile("s_waitcnt vmcnt(8)" ::: "memory");
  BARRIER_RAW();

  f32x4 acc[4][4] = {};

  #pragma unroll
  for (int t = 0; t < 8; ++t) {             // K = 8 x 32, NO in-loop barriers
    if (t < 6) {
      #pragma unroll
      for (int i = 0; i < 4; ++i) {
        const int L = i * 64 + lane;
        const int r = L >> 2, c = L & 3;
        gload_lds16(&A[(size_t)(mw + r) * ldA + (t+2)*32
                       + (c ^ ((r >> 1) & 3)) * 8],
                    &Al[w][(t + 2) % 3][0][0] + (size_t)L * 8);
      }
    }
    if (t < 6)      asm volatile("s_waitcnt vmcnt(8)" ::: "memory");
    else if (t == 6) asm volatile("s_waitcnt vmcnt(4)" ::: "memory");
    else             asm volatile("s_waitcnt vmcnt(0)" ::: "memory");

    bf16x8 af[4], bfr[4];
    #pragma unroll
    for (int mi = 0; mi < 4; ++mi) {
      const int r = mi * 16 + l15;
      af[mi] = __builtin_bit_cast(bf16x8,
          *(const u16x8*)&Al[w][t % 3][r][(g ^ ((r >> 1) & 3)) * 8]);
    }
    #pragma unroll
    for (int ni = 0; ni < 4; ++ni) {
      const int r = ni * 16 + l15;
      bfr[ni] = __builtin_bit_cast(bf16x8,
          *(const u16x8*)&Bl[r][((t*4 + g) ^ (r & 7)) * 8]);
    }
    if (vmode) {
      #pragma unroll
      for (int mi = 0; mi < 4; ++mi)
        #pragma unroll
        for (int ni = 0; ni < 4; ++ni)
          acc[mi][ni] = __builtin_amdgcn_mfma_f32_16x16x32_bf16(
                            bfr[ni], af[mi], acc[mi][ni], 0, 0, 0);
    } else {
      #pragma unroll
      for (int mi = 0; mi < 4; ++mi)
        #pragma unroll
        for (int ni = 0; ni < 4; ++ni)
          acc[mi][ni] = __builtin_amdgcn_mfma_f32_16x16x32_bf16(
                            af[mi], bfr[ni], acc[mi][ni], 0, 0, 0);
    }
  }

  #pragma unroll
  for (int mi = 0; mi < 4; ++mi)
    #pragma unroll
    for (int ni = 0; ni < 4; ++ni) {
      if (!vmode) {
        const int col = n0 + ni * 16 + l15;
        const float bv = bias[col];
        #pragma unroll
        for (int r = 0; r < 4; ++r) {
          const int row = mw + mi * 16 + g * 4 + r;
          const float v = acc[mi][ni][r] + bv;
          if (OUT_MODE == 1)
            ((float*)Outp)[(size_t)row * ldOut + col] = v;
          else
            ((ushort_t*)Outp)[(size_t)row * 512 + col] = f2bf(v);
        }
      } else {
        const int hh = (n0 - 512) >> 6;
        const int m = mw + mi * 16 + l15;
        const int bb = m >> 10, ss = m & 1023;
        ushort_t* vbase =
            &Vt[(size_t)(((bb*4 + hh)*16 + (ss >> 6)) * 4096) + (ss & 63)];
        #pragma unroll
        for (int r = 0; r < 4; ++r) {
          const int nn = n0 + ni * 16 + g * 4 + r;     // 512..767
          const float v = acc[mi][ni][r] + bias[nn];
          vbase[(size_t)((nn - 512) & 63) * 64] = f2bf(v);
        }
      }
    }
}

// ---------------- kernel 2: causal flash attention v3 -----------------------
// 1024 blocks x 1 q-tile.  qt = (lid>>3)&15; bh = (lid&7)+8*(lid>>7) ->
// XCD-pinned (8 bh per XCD, KV 2MB L2-resident).  K: gload_lds 3-ring,
// XOR-swizzled (conflict-free b128).  V: reg-staged 2-buf padded [64][72]
// (conflict-free b64).  Counted vmcnt, raw barriers, exp2f softmax.
__global__ __launch_bounds__(256, 3)
void attn_kernel(ushort_t* __restrict__ qk, const ushort_t* __restrict__ Vt)
{
  __shared__ ushort_t K_lds[3][64][64];   // 24 KB ring, chunk c at c^(r&7)
  __shared__ ushort_t V_lds[2][64][72];   // 18 KB, padded, linear

  const int lid = blockIdx.x;
  const int qt  = (lid >> 3) & 15;
  const int bh  = (lid & 7) + ((lid >> 7) << 3);
  const int h = bh & 3, b = bh >> 2;
  const int last = qt;

  const int tid = threadIdx.x;
  const int lane = tid & 63;
  const int w = tid >> 6;
  const int l15 = lane & 15, g = lane >> 4;

  const size_t rowbase = (size_t)b * 1024;
  const int qc = h * 64, kc = 256 + h * 64;
  const ushort_t* Vtt = Vt + (size_t)bh * 16 * 4096;

  // staging geometry: thread covers 16B chunks (r0,c0) and (r1,c0)
  const int r0 = tid >> 3, c0 = tid & 7;   // rows 0..31
  const int r1 = 32 + r0;                  // rows 32..63

  auto stageK = [&](int bi, int kt) {
    const int kv0 = kt * 64;
    gload_lds16(&qk[(rowbase + kv0 + r0)*512 + kc + (c0 ^ (r0 & 7))*8],
                &K_lds[bi][0][0] + (size_t)tid*8);
    gload_lds16(&qk[(rowbase + kv0 + r1)*512 + kc + (c0 ^ (r1 & 7))*8],
                &K_lds[bi][0][0] + (size_t)(tid + 256)*8);
  };
  auto loadV = [&](int kt, float4& va, float4& vb) {
    const ushort_t* vtile = Vtt + kt * 4096;
    va = *(const float4*)&vtile[r0*64 + c0*8];
    vb = *(const float4*)&vtile[r1*64 + c0*8];
  };
  auto writeV = [&](int bi, const float4& va, const float4& vb) {
    *(float4*)&V_lds[bi][r0][c0*8] = va;
    *(float4*)&V_lds[bi][r1][c0*8] = vb;
  };

  // Q fragments (B-operand of swapped QK): col=l15=q, k(d)=ks*32+g*8+j
  bf16x8 qf[2];
  {
    const size_t rq = rowbase + qt*64 + w*16 + l15;
    #pragma unroll
    for (int ks = 0; ks < 2; ++ks)
      qf[ks] = __builtin_bit_cast(bf16x8,
                 *(const u16x8*)&qk[rq*512 + qc + ks*32 + g*8]);
  }

  f32x4 o[4] = {};                     // O^T frags: row d=da*16+g*4+r, col q=l15
  float ls = 0.f;
  const int qg = qt*64 + w*16 + l15;   // this lane's q row

  float4 vA0, vA1, vB0, vB1;

  // ---- prologue ----
  loadV(0, vA0, vA1);
  stageK(0, 0);
  if (last >= 1) {
    loadV(1, vB0, vB1);
    stageK(1, 1);
    asm volatile("s_waitcnt vmcnt(4)" ::: "memory");   // V0 regs + K0 landed
  } else {
    asm volatile("s_waitcnt vmcnt(0)" ::: "memory");
  }
  writeV(0, vA0, vA1);
  asm volatile("s_waitcnt lgkmcnt(0)" ::: "memory");
  BARRIER_RAW();

  // ---- one pipeline step: compute tile KT; load kt+2 -> L*, write kt+1 <- W*
  auto step = [&](int KT, float4& L0, float4& L1, float4& W0, float4& W1) {
    const int cur3 = KT % 3, curV = KT & 1;
    const bool haveN2 = (KT + 2 <= last);
    const bool haveN1 = (KT + 1 <= last);
    if (haveN2) { loadV(KT + 2, L0, L1); stageK((KT + 2) % 3, KT + 2); }

    // K frags (A-operand): row kv=ni*16+l15, k(d)=ks*32+g*8+j
    bf16x8 kf[2][4];
    #pragma unroll
    for (int ks = 0; ks < 2; ++ks)
      #pragma unroll
      for (int ni = 0; ni < 4; ++ni) {
        const int row = ni*16 + l15;
        kf[ks][ni] = __builtin_bit_cast(bf16x8,
            *(const u16x8*)&K_lds[cur3][row][(((ks*4 + g) ^ (row & 7))) * 8]);
      }
    // V^T frags (PV mfma16 A-operand): row d=da*16+l15, k(kv)=ni*16+g*4+j
    bf16x4 vf[4][4];
    #pragma unroll
    for (int ni = 0; ni < 4; ++ni)
      #pragma unroll
      for (int da = 0; da < 4; ++da)
        vf[ni][da] = __builtin_bit_cast(bf16x4,
            *(const u16x4*)&V_lds[curV][da*16 + l15][ni*16 + g*4]);

    f32x4 s[4] = {};
    #pragma unroll
    for (int ks = 0; ks < 2; ++ks)
      #pragma unroll
      for (int ni = 0; ni < 4; ++ni)
        s[ni] = __builtin_amdgcn_mfma_f32_16x16x32_bf16(kf[ks][ni], qf[ks],
                                                        s[ni], 0, 0, 0);
    const int kv0 = KT * 64;
    const bool diag = (KT == last);
    bf16x4 pn[4];
    #pragma unroll
    for (int ni = 0; ni < 4; ++ni)
      #pragma unroll
      for (int r = 0; r < 4; ++r) {
        // exp(s/8 - 10) = exp2(s*log2e/8 - 10*log2e)
        float e = exp2f(fmaf(s[ni][r], 0.18033688011112042f,
                             -14.426950408889634f));
        if (diag) e = (kv0 + ni*16 + g*4 + r <= qg) ? e : 0.0f;
        ls += e;
        pn[ni][r] = (__bf16)e;
      }
    #pragma unroll
    for (int ni = 0; ni < 4; ++ni)
      #pragma unroll
      for (int da = 0; da < 4; ++da)
        o[da] = mfma16(vf[ni][da], pn[ni], o[da]);

    if (haveN1) {
      if (haveN2) asm volatile("s_waitcnt vmcnt(4)" ::: "memory");
      else        asm volatile("s_waitcnt vmcnt(0)" ::: "memory");
      writeV((KT + 1) & 1, W0, W1);
      asm volatile("s_waitcnt lgkmcnt(0)" ::: "memory");
      BARRIER_RAW();
    }
  };

  // double-step loop keeps the staging register sets statically indexed
  for (int kt = 0; ; ) {
    step(kt, vA0, vA1, vB0, vB1);    // even: load->A, write tile kt+1 from B
    if (++kt > last) break;
    step(kt, vB0, vB1, vA0, vA1);    // odd
    if (++kt > last) break;
  }

  // reduce lane-local row sums across the 4 g-groups (same q=l15)
  ls += __shfl_xor(ls, 16);
  ls += __shfl_xor(ls, 32);
  const float inv = 1.f / ls;

  // O^T store: lane's q row; d = da*16+g*4+r -> 8B b64 stores
  {
    const size_t rowq = rowbase + (size_t)qg;
    #pragma unroll
    for (int da = 0; da < 4; ++da) {
      u16x4 ov;
      #pragma unroll
      for (int r = 0; r < 4; ++r) ov[r] = f2bf(o[da][r] * inv);
      *(u16x4*)&qk[rowq*512 + qc + da*16 + g*4] = ov;
    }
  }
}

// ---------------- launcher --------------------------------------------------
extern "C" void kernel_launch(void* const* d_in, const int* in_sizes, int n_in,
                              void* d_out, int out_size, void* d_ws, size_t ws_size,
                              hipStream_t stream)
{
  const float* x     = (const float*)d_in[0];
  const float* W_qkv = (const float*)d_in[1];
  const float* b_qkv = (const float*)d_in[2];
  const float* W_out = (const float*)d_in[3];
  const float* b_out = (const float*)d_in[4];
  float* out = (float*)d_out;

  char* ws = (char*)d_ws;
  ushort_t* WqT = (ushort_t*)ws;                         // [768][256]
  ushort_t* WoT = (ushort_t*)(ws + 393216);              // [256][256]
  ushort_t* qk  = (ushort_t*)(ws + 524288);              // [16384][512]
  ushort_t* Vt  = (ushort_t*)(ws + 17301504);            // [64][16][64][64]
  ushort_t* xb  = (ushort_t*)(ws + 25690112);            // [16384][256]

  convert_all<<<dim3(2112), dim3(256), 0, stream>>>(x, W_qkv, W_out, xb, WqT, WoT);
  // QKV projection: 12 n-tiles x 64 m-groups
  gemm_bias<0, 12><<<dim3(768), dim3(256), 0, stream>>>(
      xb, 256, WqT, b_qkv, qk, 512, Vt);
  // causal flash attention: 1024 blocks, 1 q-tile each
  attn_kernel<<<dim3(1024), dim3(256), 0, stream>>>(qk, Vt);
  // output projection: 4 n-tiles x 64 m-groups
  gemm_bias<1, 4><<<dim3(256), dim3(256), 0, stream>>>(
      qk, 512, WoT, b_out, out, 256, nullptr);
}

// Round 12
// 65.096 us; speedup vs baseline: 2.1559x; 1.1019x over previous
//
#include <hip/hip_runtime.h>

// Attention_55336358642806: x@W_qkv+b -> 4-head causal attention -> @W_out+b
// B=16 S=1024 E=256 H=4 D=64.  All-MFMA bf16 pipeline, fp32 accumulation.
//
// GEMM v5: barrier-free wave-synchronous (r9 core). B-panel 64x256 resident
// in LDS (ONE barrier); per-wave A double-buffer reg-staged (fp32->bf16 cvt
// fused for the QKV GEMM -> x convert pass deleted). M-tile 128, 48KB LDS,
// 3 blocks/CU, grid = 2 exact generations.
// attn v4: r10's PAIRED structure (proven 17.6us) with ONLY the V path
// swapped to reg-staged padded [64][72] LDS (kills the measured 1.64M
// bank conflicts/unit; reads 2-way=free) + exp2f softmax.
//
// ws layout (bytes):
//   [0,        393216)   W_qkvT bf16 [768][256]
//   [393216,   524288)   W_outT bf16 [256][256]
//   [524288, 17301504)   qk     bf16 [16384][512]  (Q cols 0..255, K 256..511;
//                                                   attn out overwrites Q cols)
//   [17301504,25690112)  Vt     bf16 [64 bh][16 kvt][64 d][64 kv]

typedef unsigned short ushort_t;
typedef __bf16 bf16x8 __attribute__((ext_vector_type(8)));
typedef __bf16 bf16x4 __attribute__((ext_vector_type(4)));
typedef unsigned short u16x8 __attribute__((ext_vector_type(8)));
typedef unsigned short u16x4 __attribute__((ext_vector_type(4)));
typedef float f32x4 __attribute__((ext_vector_type(4)));
typedef short s16x4 __attribute__((ext_vector_type(4)));

__device__ __forceinline__ ushort_t f2bf(float f) {
  __bf16 h = (__bf16)f;
  return __builtin_bit_cast(ushort_t, h);
}

__device__ __forceinline__ void gload_lds16(const ushort_t* g, ushort_t* l) {
  __builtin_amdgcn_global_load_lds(
      (const __attribute__((address_space(1))) unsigned int*)g,
      (__attribute__((address_space(3))) unsigned int*)l, 16, 0, 0);
}

#define BARRIER_RAW() do { __builtin_amdgcn_s_barrier(); \
                           __builtin_amdgcn_sched_barrier(0); } while (0)

__device__ __forceinline__ f32x4 mfma16(bf16x4 a, bf16x4 b, f32x4 c) {
#if __has_builtin(__builtin_amdgcn_mfma_f32_16x16x16bf16_1k)
  return __builtin_amdgcn_mfma_f32_16x16x16bf16_1k(
      __builtin_bit_cast(s16x4, a), __builtin_bit_cast(s16x4, b), c, 0, 0, 0);
#elif __has_builtin(__builtin_amdgcn_mfma_f32_16x16x16_bf16)
  return __builtin_amdgcn_mfma_f32_16x16x16_bf16(a, b, c, 0, 0, 0);
#else
  f32x4 d = c;
  asm volatile("v_mfma_f32_16x16x16_bf16 %0, %1, %2, %0"
               : "+v"(d) : "v"(a), "v"(b));
  return d;
#endif
}

// ------------- kernel 0: weight transpose+convert only ----------------------
__global__ __launch_bounds__(256)
void convert_wt(const float* __restrict__ Wq, const float* __restrict__ Wo,
                ushort_t* __restrict__ WqT, ushort_t* __restrict__ WoT)
{
  __shared__ float t[64][65];
  int blk = blockIdx.x;
  const float* src; ushort_t* dst; int ld_src, k0, n0;
  if (blk < 48) { src = Wq; dst = WqT; ld_src = 768;
                  k0 = (blk / 12) * 64; n0 = (blk % 12) * 64; }
  else { blk -= 48; src = Wo; dst = WoT; ld_src = 256;
         k0 = (blk / 4) * 64; n0 = (blk % 4) * 64; }
  const int tr = threadIdx.x >> 6, tc = threadIdx.x & 63;
  #pragma unroll
  for (int i = 0; i < 16; ++i) {
    const int r = i * 4 + tr;
    t[r][tc] = src[(size_t)(k0 + r) * ld_src + n0 + tc];
  }
  __syncthreads();
  #pragma unroll
  for (int i = 0; i < 16; ++i) {
    const int r = i * 4 + tr;
    dst[(size_t)(n0 + r) * 256 + k0 + tc] = f2bf(t[tc][r]);
  }
}

// ---------------- GEMM v5: C[M][N] = A[M][256] * Bt[N][256]^T + bias --------
// Block: 4 waves, tile 128M x 64N; wave w owns rows [mBase+w*32, +32).
// Bl resident (ONE barrier).  A: per-wave 2-buf reg-staged (fp32 cvt fused
// when A_F32), counted per-wave vmcnt, NO in-loop barriers, 8 unrolled steps.
template<int A_F32, int OUT_MODE, int NB>  // OUT_MODE: 0=qkv split, 1=f32
__global__ __launch_bounds__(256, 3)
void gemm_bias(const void* __restrict__ Ap, int ldA,
               const ushort_t* __restrict__ Bt,
               const float* __restrict__ bias,
               void* __restrict__ Outp, int ldOut,
               ushort_t* __restrict__ Vt)
{
  __shared__ ushort_t Bl[64][256];          // 32 KB; 16B-chunk c at c^(r&7)
  __shared__ ushort_t Al[4][2][32][32];     // 16 KB; slot p holds chunk p^((r>>1)&3)

  const int tid = threadIdx.x;
  const int lane = tid & 63;
  const int w  = tid >> 6;
  const int l15 = lane & 15, g = lane >> 4;

  const int nwg = NB * 128;
  const int inner = (int)blockIdx.x;
  const int chunkXCD = nwg >> 3;
  const int gidx = (inner & 7) * chunkXCD + (inner >> 3);
  const int n0 = (gidx % NB) * 64;
  const int mBase = (gidx / NB) * 128;
  const int mw = mBase + w * 32;            // this wave's 32 rows
  const bool vmode = (OUT_MODE == 0) && (n0 >= 512);

  // A staging geometry: lane owns physical slots (ar0,ac) and (ar1,ac)
  const int ar0 = lane >> 2, ar1 = 16 + ar0, ac = lane & 3;
  const int acc0 = ac ^ ((ar0 >> 1) & 3);
  const int acc1 = ac ^ ((ar1 >> 1) & 3);

  auto loadA = [&](int t, float4& f0, float4& f1, float4& f2, float4& f3) {
    if constexpr (A_F32) {
      const float* Af = (const float*)Ap;
      const float* p0 = &Af[(size_t)(mw + ar0) * ldA + t*32 + acc0*8];
      const float* p1 = &Af[(size_t)(mw + ar1) * ldA + t*32 + acc1*8];
      f0 = *(const float4*)p0; f1 = *(const float4*)(p0 + 4);
      f2 = *(const float4*)p1; f3 = *(const float4*)(p1 + 4);
    } else {
      const ushort_t* Ab = (const ushort_t*)Ap;
      f0 = *(const float4*)&Ab[(size_t)(mw + ar0) * ldA + t*32 + acc0*8];
      f2 = *(const float4*)&Ab[(size_t)(mw + ar1) * ldA + t*32 + acc1*8];
    }
  };
  auto writeA = [&](int buf, const float4& f0, const float4& f1,
                    const float4& f2, const float4& f3) {
    u16x8 u0, u1;
    if constexpr (A_F32) {
      u0[0]=f2bf(f0.x); u0[1]=f2bf(f0.y); u0[2]=f2bf(f0.z); u0[3]=f2bf(f0.w);
      u0[4]=f2bf(f1.x); u0[5]=f2bf(f1.y); u0[6]=f2bf(f1.z); u0[7]=f2bf(f1.w);
      u1[0]=f2bf(f2.x); u1[1]=f2bf(f2.y); u1[2]=f2bf(f2.z); u1[3]=f2bf(f2.w);
      u1[4]=f2bf(f3.x); u1[5]=f2bf(f3.y); u1[6]=f2bf(f3.z); u1[7]=f2bf(f3.w);
    } else {
      u0 = __builtin_bit_cast(u16x8, f0);
      u1 = __builtin_bit_cast(u16x8, f2);
    }
    *(u16x8*)&Al[w][buf][ar0][ac*8] = u0;
    *(u16x8*)&Al[w][buf][ar1][ac*8] = u1;
  };
  #define VMCNT_A() do { if constexpr (A_F32) \
      asm volatile("s_waitcnt vmcnt(4)" ::: "memory"); \
    else asm volatile("s_waitcnt vmcnt(2)" ::: "memory"); } while (0)

  // ---- B resident stage (block-cooperative) ----
  #pragma unroll
  for (int i = 0; i < 8; ++i) {
    const int L = i * 256 + tid;
    const int r = L >> 5, c = L & 31;
    gload_lds16(&Bt[(size_t)(n0 + r) * 256 + (c ^ (r & 7)) * 8],
                &Bl[0][0] + (size_t)L * 8);
  }
  float4 a0, a1, a2, a3, b0, b1, b2, b3;
  loadA(0, a0, a1, a2, a3);
  loadA(1, b0, b1, b2, b3);
  VMCNT_A();                                 // B + slice0 landed
  writeA(0, a0, a1, a2, a3);
  asm volatile("s_waitcnt lgkmcnt(0)" ::: "memory");
  BARRIER_RAW();                             // B visible to all waves

  f32x4 acc[2][4] = {};

  #pragma unroll
  for (int t = 0; t < 8; ++t) {              // NO in-loop barriers
    if (t < 6) {
      if (t & 1) loadA(t + 2, b0, b1, b2, b3);
      else       loadA(t + 2, a0, a1, a2, a3);
    }
    bf16x8 af[2], bfr[4];
    #pragma unroll
    for (int mi = 0; mi < 2; ++mi) {
      const int r = mi * 16 + l15;
      af[mi] = __builtin_bit_cast(bf16x8,
          *(const u16x8*)&Al[w][t & 1][r][(g ^ ((r >> 1) & 3)) * 8]);
    }
    #pragma unroll
    for (int ni = 0; ni < 4; ++ni) {
      const int r = ni * 16 + l15;
      bfr[ni] = __builtin_bit_cast(bf16x8,
          *(const u16x8*)&Bl[r][((t*4 + g) ^ (r & 7)) * 8]);
    }
    if (vmode) {
      #pragma unroll
      for (int mi = 0; mi < 2; ++mi)
        #pragma unroll
        for (int ni = 0; ni < 4; ++ni)
          acc[mi][ni] = __builtin_amdgcn_mfma_f32_16x16x32_bf16(
                            bfr[ni], af[mi], acc[mi][ni], 0, 0, 0);
    } else {
      #pragma unroll
      for (int mi = 0; mi < 2; ++mi)
        #pragma unroll
        for (int ni = 0; ni < 4; ++ni)
          acc[mi][ni] = __builtin_amdgcn_mfma_f32_16x16x32_bf16(
                            af[mi], bfr[ni], acc[mi][ni], 0, 0, 0);
    }
    if (t < 6) VMCNT_A();
    else if (t == 6) asm volatile("s_waitcnt vmcnt(0)" ::: "memory");
    if (t < 7) {
      if (t & 1) writeA((t + 1) & 1, a0, a1, a2, a3);
      else       writeA((t + 1) & 1, b0, b1, b2, b3);
      asm volatile("s_waitcnt lgkmcnt(0)" ::: "memory");
    }
  }

  // ---- epilogue: C/D layout row = g*4+r, col = l15 ----
  #pragma unroll
  for (int mi = 0; mi < 2; ++mi)
    #pragma unroll
    for (int ni = 0; ni < 4; ++ni) {
      if (!vmode) {
        const int col = n0 + ni * 16 + l15;
        const float bv = bias[col];
        #pragma unroll
        for (int r = 0; r < 4; ++r) {
          const int row = mw + mi * 16 + g * 4 + r;
          const float v = acc[mi][ni][r] + bv;
          if (OUT_MODE == 1)
            ((float*)Outp)[(size_t)row * ldOut + col] = v;
          else
            ((ushort_t*)Outp)[(size_t)row * 512 + col] = f2bf(v);
        }
      } else {
        // swapped MFMA: D row = n (d-dim), D col = m (seq) -> coalesced Vt
        const int hh = (n0 - 512) >> 6;
        const int m = mw + mi * 16 + l15;
        const int bb = m >> 10, ss = m & 1023;
        ushort_t* vbase =
            &Vt[(size_t)(((bb*4 + hh)*16 + (ss >> 6)) * 4096) + (ss & 63)];
        #pragma unroll
        for (int r = 0; r < 4; ++r) {
          const int nn = n0 + ni * 16 + g * 4 + r;     // 512..767
          const float v = acc[mi][ni][r] + bias[nn];
          vbase[(size_t)((nn - 512) & 63) * 64] = f2bf(v);
        }
      }
    }
  #undef VMCNT_A
}

// ---------------- kernel 2: causal flash attention v4 -----------------------
// r10 PAIRED structure: 512 blocks, p=(lid>>3)&7 -> q-tiles {p,15-p} (17
// tile-computes, balanced, 2x K/V reuse); bh=(lid&7)+8*(lid>>6) XCD-pinned.
// K: gload_lds 3-ring XOR-swizzled (proven conflict-free b128).
// V: reg-staged 2-buf PADDED [64][72] (fixes r10's 1.64M 4-way conflicts).
// Counted vmcnt(4), raw barriers, exp2f softmax, P in registers (mfma16 PV).
__global__ __launch_bounds__(256, 2)
void attn_kernel(ushort_t* __restrict__ qk, const ushort_t* __restrict__ Vt)
{
  __shared__ ushort_t K_lds[3][64][64];   // 24 KB ring, chunk c at c^(r&7)
  __shared__ ushort_t V_lds[2][64][72];   // 18 KB, padded, linear (V^T tiles)

  const int lid = blockIdx.x;
  const int p   = (lid >> 3) & 7;
  const int bh  = (lid & 7) + ((lid >> 6) << 3);
  const int h = bh & 3, b = bh >> 2;
  const int qtA = p, qtB = 15 - p;

  const int tid = threadIdx.x;
  const int lane = tid & 63;
  const int w = tid >> 6;
  const int l15 = lane & 15, g = lane >> 4;

  const size_t rowbase = (size_t)b * 1024;
  const int qc = h * 64, kc = 256 + h * 64;
  const ushort_t* Vtt = Vt + (size_t)bh * 16 * 4096;

  // staging geometry
  const int kr0 = tid >> 3, kc0 = tid & 7;     // K: rows 0..31 / 32..63
  const int kr1 = 32 + kr0;
  const int vr0 = tid >> 3, vc0 = tid & 7;     // V: same split, padded dest

  auto stageK = [&](int bi, int kt) {
    const int kv0 = kt * 64;
    gload_lds16(&qk[(rowbase + kv0 + kr0)*512 + kc + (kc0 ^ (kr0 & 7))*8],
                &K_lds[bi][0][0] + (size_t)tid*8);
    gload_lds16(&qk[(rowbase + kv0 + kr1)*512 + kc + (kc0 ^ (kr1 & 7))*8],
                &K_lds[bi][0][0] + (size_t)(tid + 256)*8);
  };
  auto loadV = [&](int kt, float4& va, float4& vb) {
    const ushort_t* vtile = Vtt + kt * 4096;
    va = *(const float4*)&vtile[vr0*64 + vc0*8];
    vb = *(const float4*)&vtile[(32 + vr0)*64 + vc0*8];
  };
  auto writeV = [&](int bi, const float4& va, const float4& vb) {
    *(float4*)&V_lds[bi][vr0][vc0*8] = va;
    *(float4*)&V_lds[bi][32 + vr0][vc0*8] = vb;
  };

  // Q fragments (B-operand of swapped QK): col=l15=q, k(d)=ks*32+g*8+j
  bf16x8 qfA[2], qfB[2];
  {
    const size_t ra = rowbase + qtA*64 + w*16 + l15;
    const size_t rb = rowbase + qtB*64 + w*16 + l15;
    #pragma unroll
    for (int ks = 0; ks < 2; ++ks) {
      qfA[ks] = __builtin_bit_cast(bf16x8,
                  *(const u16x8*)&qk[ra*512 + qc + ks*32 + g*8]);
      qfB[ks] = __builtin_bit_cast(bf16x8,
                  *(const u16x8*)&qk[rb*512 + qc + ks*32 + g*8]);
    }
  }

  f32x4 oA[4] = {}, oB[4] = {};        // O^T frags: row d=da*16+g*4+r, col q=l15
  float lsA = 0.f, lsB = 0.f;
  const int qgA = qtA*64 + w*16 + l15;
  const int qgB = qtB*64 + w*16 + l15;

  float4 vA0, vA1, vB0, vB1;

  // ---- prologue (qtB >= 8 so tiles 0 and 1 always exist) ----
  stageK(0, 0); loadV(0, vA0, vA1);
  stageK(1, 1); loadV(1, vB0, vB1);
  asm volatile("s_waitcnt vmcnt(4)" ::: "memory");   // batch0 landed
  writeV(0, vA0, vA1);
  asm volatile("s_waitcnt lgkmcnt(0)" ::: "memory");
  BARRIER_RAW();

  auto step = [&](int KT, float4& L0, float4& L1, float4& W0, float4& W1) {
    const int cur3 = KT % 3, curV = KT & 1;
    const bool haveN2 = (KT + 2 <= qtB);
    const bool haveN1 = (KT + 1 <= qtB);
    if (haveN2) { stageK((KT + 2) % 3, KT + 2); loadV(KT + 2, L0, L1); }

    // K frags (A-operand): row kv=ni*16+l15, k(d)=ks*32+g*8+j
    bf16x8 kf[2][4];
    #pragma unroll
    for (int ks = 0; ks < 2; ++ks)
      #pragma unroll
      for (int ni = 0; ni < 4; ++ni) {
        const int row = ni*16 + l15;
        kf[ks][ni] = __builtin_bit_cast(bf16x8,
            *(const u16x8*)&K_lds[cur3][row][(((ks*4 + g) ^ (row & 7))) * 8]);
      }
    // V^T frags (PV mfma16 A-operand): row d=da*16+l15, k(kv)=ni*16+g*4+j
    bf16x4 vf[4][4];
    #pragma unroll
    for (int ni = 0; ni < 4; ++ni)
      #pragma unroll
      for (int da = 0; da < 4; ++da)
        vf[ni][da] = __builtin_bit_cast(bf16x4,
            *(const u16x4*)&V_lds[curV][da*16 + l15][ni*16 + g*4]);

    const int kv0 = KT * 64;
    auto tile_step = [&](const bf16x8 (&qf)[2], f32x4 (&o)[4], float &ls,
                         int qg, bool diag) {
      f32x4 s[4] = {};
      #pragma unroll
      for (int ks = 0; ks < 2; ++ks)
        #pragma unroll
        for (int ni = 0; ni < 4; ++ni)
          s[ni] = __builtin_amdgcn_mfma_f32_16x16x32_bf16(kf[ks][ni], qf[ks],
                                                          s[ni], 0, 0, 0);
      bf16x4 pn[4];
      #pragma unroll
      for (int ni = 0; ni < 4; ++ni)
        #pragma unroll
        for (int r = 0; r < 4; ++r) {
          // exp(s/8 - 10) = exp2(s*log2e/8 - 10*log2e)
          float e = exp2f(fmaf(s[ni][r], 0.18033688011112042f,
                               -14.426950408889634f));
          if (diag) e = (kv0 + ni*16 + g*4 + r <= qg) ? e : 0.0f;
          ls += e;
          pn[ni][r] = (__bf16)e;
        }
      #pragma unroll
      for (int ni = 0; ni < 4; ++ni)
        #pragma unroll
        for (int da = 0; da < 4; ++da)
          o[da] = mfma16(vf[ni][da], pn[ni], o[da]);
    };

    tile_step(qfB, oB, lsB, qgB, KT == qtB);
    if (KT <= qtA) tile_step(qfA, oA, lsA, qgA, KT == qtA);

    if (haveN1) {
      if (haveN2) asm volatile("s_waitcnt vmcnt(4)" ::: "memory");
      else        asm volatile("s_waitcnt vmcnt(0)" ::: "memory");
      writeV((KT + 1) & 1, W0, W1);
      asm volatile("s_waitcnt lgkmcnt(0)" ::: "memory");
      BARRIER_RAW();
    }
  };

  // double-step keeps staging register sets statically indexed
  for (int kt = 0; ; ) {
    step(kt, vA0, vA1, vB0, vB1);
    if (++kt > qtB) break;
    step(kt, vB0, vB1, vA0, vA1);
    if (++kt > qtB) break;
  }

  asm volatile("s_nop 7\n\ts_nop 7" :::);

  lsA += __shfl_xor(lsA, 16); lsA += __shfl_xor(lsA, 32);
  lsB += __shfl_xor(lsB, 16); lsB += __shfl_xor(lsB, 32);
  const float invA = 1.f / lsA;
  const float invB = 1.f / lsB;

  // O^T store: lane's q row; d = da*16+g*4+r -> 8B b64 stores
  {
    const size_t rowA = rowbase + (size_t)qgA;
    const size_t rowB = rowbase + (size_t)qgB;
    #pragma unroll
    for (int da = 0; da < 4; ++da) {
      u16x4 ovA, ovB;
      #pragma unroll
      for (int r = 0; r < 4; ++r) {
        ovA[r] = f2bf(oA[da][r] * invA);
        ovB[r] = f2bf(oB[da][r] * invB);
      }
      *(u16x4*)&qk[rowA*512 + qc + da*16 + g*4] = ovA;
      *(u16x4*)&qk[rowB*512 + qc + da*16 + g*4] = ovB;
    }
  }
}

// ---------------- launcher --------------------------------------------------
extern "C" void kernel_launch(void* const* d_in, const int* in_sizes, int n_in,
                              void* d_out, int out_size, void* d_ws, size_t ws_size,
                              hipStream_t stream)
{
  const float* x     = (const float*)d_in[0];
  const float* W_qkv = (const float*)d_in[1];
  const float* b_qkv = (const float*)d_in[2];
  const float* W_out = (const float*)d_in[3];
  const float* b_out = (const float*)d_in[4];
  float* out = (float*)d_out;

  char* ws = (char*)d_ws;
  ushort_t* WqT = (ushort_t*)ws;                         // [768][256]
  ushort_t* WoT = (ushort_t*)(ws + 393216);              // [256][256]
  ushort_t* qk  = (ushort_t*)(ws + 524288);              // [16384][512]
  ushort_t* Vt  = (ushort_t*)(ws + 17301504);            // [64][16][64][64]

  convert_wt<<<dim3(64), dim3(256), 0, stream>>>(W_qkv, W_out, WqT, WoT);
  // QKV projection, x fp32 consumed directly (cvt fused into A staging):
  // 12 n-tiles x 128 m-groups = 1536 blocks (2 exact generations at 3/CU)
  gemm_bias<1, 0, 12><<<dim3(1536), dim3(256), 0, stream>>>(
      x, 256, WqT, b_qkv, qk, 512, Vt);
  // causal flash attention (paired q-tiles, padded V LDS)
  attn_kernel<<<dim3(512), dim3(256), 0, stream>>>(qk, Vt);
  // output projection: 4 n-tiles x 128 m-groups = 512 blocks
  gemm_bias<0, 1, 4><<<dim3(512), dim3(256), 0, stream>>>(
      qk, 512, WoT, b_out, out, 256, nullptr);
}